// Round 4
// baseline (135.900 us; speedup 1.0000x reference)
//
#include <hip/hip_runtime.h>

typedef unsigned int   u32;
typedef unsigned short u16;
typedef _Float16       f16;

using f16x8 = __attribute__((ext_vector_type(8))) _Float16;
using f32x4 = __attribute__((ext_vector_type(4))) float;

#define LLDS16(G, L) __builtin_amdgcn_global_load_lds( \
  (const __attribute__((address_space(1))) u32*)(G), \
  (__attribute__((address_space(3))) u32*)(L), 16, 0, 0)

#define WAITV(N) { asm volatile("s_waitcnt vmcnt(" #N ")" ::: "memory"); \
                   __builtin_amdgcn_sched_barrier(0); }
#define FENCE_BAR() { asm volatile("s_waitcnt lgkmcnt(0)" ::: "memory"); \
                      __builtin_amdgcn_sched_barrier(0); \
                      __builtin_amdgcn_s_barrier(); \
                      __builtin_amdgcn_sched_barrier(0); }
#define BAR() { __builtin_amdgcn_s_barrier(); __builtin_amdgcn_sched_barrier(0); }

// ---------------- transpose (R,32) f32 -> (32,R) f16 ----------------
__global__ __launch_bounds__(256)
void transpose32(const float* __restrict__ in, f16* __restrict__ out, int R){
  __shared__ float tile[32][33];
  const int tid = threadIdx.x;
  const int r0  = blockIdx.x << 5;
  const int c   = tid & 31;
  const int rp  = tid >> 5;
#pragma unroll
  for (int p = 0; p < 4; ++p){
    const int r = (p << 3) + rp;
    tile[r][c] = in[(size_t)(r0 + r) * 32 + c];
  }
  __syncthreads();
#pragma unroll
  for (int p = 0; p < 4; ++p){
    const int dd = (p << 3) + rp;
    out[(size_t)dd * R + r0 + c] = (f16)tile[c][dd];
  }
}

// ------- W (64,K,32) f32 -> k-panel Wp [32][K/8][64][8] f16 -------
__global__ __launch_bounds__(256)
void wprep(const float* __restrict__ in, f16* __restrict__ out, int K){
  __shared__ u16 t[32 * 530];
  const int kb  = blockIdx.x;           // 0..K/8-1
  const int tid = threadIdx.x;
  const int kbase = kb << 3;
#pragma unroll 4
  for (int i = 0; i < 64; ++i){
    const int idx = tid + (i << 8);
    const int o   = idx >> 8;
    const int rem = idx & 255;
    const int e   = rem >> 5;
    const int dd  = rem & 31;
    const float v = in[(size_t)o * (K * 32) + (size_t)(kbase + e) * 32 + dd];
    union { f16 h; u16 u; } cv; cv.h = (f16)v;
    t[dd * 530 + o * 8 + e] = cv.u;
  }
  __syncthreads();
  const u32* t32 = (const u32*)t;
  u32* o32 = (u32*)out;
  const int obase = kb << 8;
#pragma unroll 4
  for (int i = 0; i < 32; ++i){
    const int idx = tid + (i << 8);
    const int dd  = idx >> 8;
    const int rem = idx & 255;
    o32[(size_t)dd * (K * 32) + obase + rem] = t32[dd * 265 + rem];
  }
}

// ---------------- CIN step: LDS-B pipelined MFMA GEMM ----------------
// y[d][b][o] = relu(bias[o] + sum_k xk[b,k/40] * x0[b,k%40] * W[d][o][k])
// Block: 128 rows x 64 cols, 4 waves (2 row-halves x 2 col-halves).
// Wave tile: 64 rows (4 strips) x 32 cols.  BK=160 (5 ksubs), dbuf LDS B.
template<int H>
__global__ __launch_bounds__(256, 2)
void cin_gemm(const f16* __restrict__ xt,     // [32][2048*40] f16
              const f16* __restrict__ xkt,    // [32][2048*64] f16 (H==64)
              const f16* __restrict__ Wp,     // [32][K/8][64][8] f16
              const float* __restrict__ bias, // [64]
              f16*       __restrict__ yt)     // [32][2048][64] f16
{
  constexpr int K     = H * 40;
  constexpr int NSTEP = K / 160;        // 10 (H=40) or 16 (H=64)
  const int bid = blockIdx.x;
  const int d   = ((bid & 7) << 2) | (bid >> 7);   // XCD-local d groups
  const int bt  = (bid >> 3) & 15;
  const int b0  = bt << 7;
  const int tid = threadIdx.x;
  const int wv  = tid >> 6;
  const int wr  = wv >> 1;
  const int wn  = wv & 1;
  const int l   = tid & 63;
  const int lg  = l >> 4;
  const int ll  = l & 15;

  __shared__ char smem[40960];          // 2 x 20KB B tiles; buf0 reused as ylds

#define AB_TILE(P, BUFOFF) do { \
  _Pragma("unroll") \
  for (int s = 0; s < 5; ++s){ \
    const f16x8 bf0 = *(const f16x8*)(smem + (BUFOFF) + vb + s*4096); \
    const f16x8 bf1 = *(const f16x8*)(smem + (BUFOFF) + vb + s*4096 + 256); \
    _Pragma("unroll") \
    for (int m = 0; m < 4; ++m){ \
      f16 xa; \
      if (s == 0)      xa = xh8[m][(P)*4 + 0]; \
      else if (s == 4) xa = xh8[m][(P)*4 + 3]; \
      else             xa = (lg >= s) ? xh8[m][(P)*4 + s] : xh8[m][(P)*4 + s - 1]; \
      const f16x8 xs = {xa, xa, xa, xa, xa, xa, xa, xa}; \
      const f16x8 av = sl[m][s] * xs; \
      acc[m][0] = __builtin_amdgcn_mfma_f32_16x16x32_f16(av, bf0, acc[m][0], 0, 0, 0); \
      acc[m][1] = __builtin_amdgcn_mfma_f32_16x16x32_f16(av, bf1, acc[m][1], 0, 0, 0); \
    } \
  } \
} while (0)

  // ---- global W per-lane pointer (streams k-panel tiles of 20KB) ----
  const f16* gW = Wp + (size_t)d * (K * 64) + wv * 2560 + l * 8;
  char* lp0 = smem + wv * 5120;
  char* lp1 = smem + 20480 + wv * 5120;

  // ---- A-row pointers (4 strips of 16 rows) ----
  const f16* x0r[4];
  const f16* xhr[4];
#pragma unroll
  for (int m = 0; m < 4; ++m){
    const int row = b0 + wr * 64 + m * 16 + ll;
    x0r[m] = xt + (size_t)d * 81920 + row * 40;
    xhr[m] = (H == 64) ? (xkt + (size_t)d * 131072 + row * 64) : x0r[m];
  }

  // ---- prologue: sl slots + xh group0 + tiles 0,1 ----
  f16x8 sl[4][5];
#pragma unroll
  for (int m = 0; m < 4; ++m)
#pragma unroll
    for (int t = 0; t < 5; ++t){
      const int j = (4 * t + lg) % 5;
      sl[m][t] = *(const f16x8*)(x0r[m] + j * 8);
    }
  f16x8 xh8[4], xh8n[4];
#pragma unroll
  for (int m = 0; m < 4; ++m){ xh8[m] = *(const f16x8*)xhr[m]; xhr[m] += 8; }
#pragma unroll
  for (int m = 0; m < 4; ++m) xh8n[m] = xh8[m];

#pragma unroll
  for (int i = 0; i < 5; ++i) LLDS16(gW + i * 512, lp0 + i * 1024);
  gW += 10240;
#pragma unroll
  for (int i = 0; i < 5; ++i) LLDS16(gW + i * 512, lp1 + i * 1024);
  gW += 10240;

  const f32x4 fz = {0.f, 0.f, 0.f, 0.f};
  f32x4 acc[4][2];
#pragma unroll
  for (int m = 0; m < 4; ++m){ acc[m][0] = fz; acc[m][1] = fz; }

  const int vb = lg * 1024 + wn * 512 + ll * 16;

  WAITV(5);                             // sl, xh0, tile0 landed; tile1 in flight
  BAR();

  for (int kk = 0; kk < NSTEP; kk += 2){
    // ---------- tile A: ks=kk, buf0 ----------
    const bool pfA = (kk + 2 < NSTEP);
    if (pfA){                           // prefetch next xh group (global, vmcnt)
#pragma unroll
      for (int m = 0; m < 4; ++m){ xh8n[m] = *(const f16x8*)xhr[m]; xhr[m] += 8; }
    }
    AB_TILE(0, 0);
    FENCE_BAR();                        // readers of buf0 done
    if (pfA){
#pragma unroll
      for (int i = 0; i < 5; ++i) LLDS16(gW + i * 512, lp0 + i * 1024);
      gW += 10240;
      WAITV(5);                         // tile kk+1 (and xh) landed
    } else { WAITV(0); }
    BAR();

    // ---------- tile B: ks=kk+1, buf1 ----------
    AB_TILE(1, 20480);
    FENCE_BAR();
    if (kk + 3 < NSTEP){
#pragma unroll
      for (int i = 0; i < 5; ++i) LLDS16(gW + i * 512, lp1 + i * 1024);
      gW += 10240;
      WAITV(5);
    } else { WAITV(0); }
    BAR();

#pragma unroll
    for (int m = 0; m < 4; ++m) xh8[m] = xh8n[m];
  }

  // ---- epilogue: bias+relu -> per-wave LDS tile (overlay buf0) -> 16B stores
  const float bv0 = bias[wn * 32 + ll];
  const float bv1 = bias[wn * 32 + 16 + ll];
  f16* yw = (f16*)(smem + wv * 5120);   // [64][40] f16
#pragma unroll
  for (int m = 0; m < 4; ++m)
#pragma unroll
    for (int n = 0; n < 2; ++n)
#pragma unroll
      for (int r = 0; r < 4; ++r){
        const int row = m * 16 + lg * 4 + r;
        const int col = n * 16 + ll;
        float v = acc[m][n][r] + (n ? bv1 : bv0);
        v = v > 0.f ? v : 0.f;
        yw[row * 40 + col] = (f16)v;
      }
  {
    const int row16 = l >> 2, ch = l & 3;
    f16* ydst = yt + (size_t)d * 131072;
#pragma unroll
    for (int j = 0; j < 4; ++j){
      const f16x8 vv = *(const f16x8*)(yw + (j * 16 + row16) * 40 + ch * 8);
      *(f16x8*)(ydst + (size_t)(b0 + wr * 64 + j * 16 + row16) * 64 + wn * 32 + ch * 8) = vv;
    }
  }
#undef AB_TILE
}

// ---------------- final: out[b, :] = sum_d concat(x, x1, x2) ----------------
__global__ __launch_bounds__(192)
void finalize(const float* __restrict__ x, const f16* __restrict__ x1t,
              const f16* __restrict__ y2t, float* __restrict__ out){
  const int b = blockIdx.x;
  const int t = threadIdx.x;
  if (t < 40){
    const float4* p = (const float4*)(x + ((size_t)b * 40 + t) * 32);
    float s = 0.f;
#pragma unroll
    for (int q = 0; q < 8; ++q){
      const float4 v = p[q];
      s += v.x + v.y + v.z + v.w;
    }
    out[(size_t)b * 168 + t] = s;
  } else if (t < 104){
    const int o = t - 40;
    float s = 0.f;
#pragma unroll
    for (int d = 0; d < 32; ++d) s += (float)x1t[(size_t)d * 131072 + (size_t)b * 64 + o];
    out[(size_t)b * 168 + t] = s;
  } else if (t < 168){
    const int o = t - 104;
    float s = 0.f;
#pragma unroll
    for (int d = 0; d < 32; ++d) s += (float)y2t[(size_t)d * 131072 + (size_t)b * 64 + o];
    out[(size_t)b * 168 + t] = s;
  }
}

extern "C" void kernel_launch(void* const* d_in, const int* in_sizes, int n_in,
                              void* d_out, int out_size, void* d_ws, size_t ws_size,
                              hipStream_t stream){
  const float* x   = (const float*)d_in[0];
  const float* W0  = (const float*)d_in[1];
  const float* b0v = (const float*)d_in[2];
  const float* W1  = (const float*)d_in[3];
  const float* b1v = (const float*)d_in[4];
  float* out = (float*)d_out;

  char* ws = (char*)d_ws;
  f16* xt  = (f16*)(ws + 0);            // 32*2048*40*2  =  5,242,880
  f16* W0p = (f16*)(ws + 5242880);      // 32*64*1600*2  =  6,553,600
  f16* W1p = (f16*)(ws + 11796480);     // 32*64*2560*2  = 10,485,760
  f16* x1t = (f16*)(ws + 22282240);     // 32*2048*64*2  =  8,388,608
  f16* y2t = (f16*)(ws + 30670848);     // 32*2048*64*2  =  8,388,608

  transpose32<<<2560, 256, 0, stream>>>(x, xt, 81920);
  wprep<<<200, 256, 0, stream>>>(W0, W0p, 1600);
  wprep<<<320, 256, 0, stream>>>(W1, W1p, 2560);

  cin_gemm<40><<<512, 256, 0, stream>>>(xt, nullptr, W0p, b0v, x1t);
  cin_gemm<64><<<512, 256, 0, stream>>>(xt, x1t,     W1p, b1v, y2t);

  finalize<<<2048, 192, 0, stream>>>(x, x1t, y2t, out);
}

// Round 5
// 97.258 us; speedup vs baseline: 1.3973x; 1.3973x over previous
//
#include <hip/hip_runtime.h>

typedef unsigned int   u32;
typedef unsigned short u16;
typedef _Float16       f16;

using f16x8 = __attribute__((ext_vector_type(8))) _Float16;
using f32x4 = __attribute__((ext_vector_type(4))) float;

#define LLDS16(G, L) __builtin_amdgcn_global_load_lds( \
  (const __attribute__((address_space(1))) u32*)(G), \
  (__attribute__((address_space(3))) u32*)(L), 16, 0, 0)

#define WAITV(N) { asm volatile("s_waitcnt vmcnt(" #N ")" ::: "memory"); \
                   __builtin_amdgcn_sched_barrier(0); }
#define FENCE_BAR() { asm volatile("s_waitcnt lgkmcnt(0)" ::: "memory"); \
                      __builtin_amdgcn_sched_barrier(0); \
                      __builtin_amdgcn_s_barrier(); \
                      __builtin_amdgcn_sched_barrier(0); }
#define BAR() { __builtin_amdgcn_s_barrier(); __builtin_amdgcn_sched_barrier(0); }

// ---------------- transpose (R,32) f32 -> (32,R) f16 ----------------
__global__ __launch_bounds__(256)
void transpose32(const float* __restrict__ in, f16* __restrict__ out, int R){
  __shared__ float tile[32][33];
  const int tid = threadIdx.x;
  const int r0  = blockIdx.x << 5;
  const int c   = tid & 31;
  const int rp  = tid >> 5;
#pragma unroll
  for (int p = 0; p < 4; ++p){
    const int r = (p << 3) + rp;
    tile[r][c] = in[(size_t)(r0 + r) * 32 + c];
  }
  __syncthreads();
#pragma unroll
  for (int p = 0; p < 4; ++p){
    const int dd = (p << 3) + rp;
    out[(size_t)dd * R + r0 + c] = (f16)tile[c][dd];
  }
}

// ------- W (64,K,32) f32 -> k-panel Wp [32][K/8][64'][8] f16, o'=o^(kb&3) ----
__global__ __launch_bounds__(256)
void wprep(const float* __restrict__ in, f16* __restrict__ out, int K){
  __shared__ u16 t[32 * 530];
  const int kb  = blockIdx.x;           // 0..K/8-1
  const int tid = threadIdx.x;
  const int kbase = kb << 3;
#pragma unroll 4
  for (int i = 0; i < 64; ++i){
    const int idx = tid + (i << 8);
    const int o   = idx >> 8;
    const int rem = idx & 255;
    const int e   = rem >> 5;
    const int dd  = rem & 31;
    const float v = in[(size_t)o * (K * 32) + (size_t)(kbase + e) * 32 + dd];
    union { f16 h; u16 u; } cv; cv.h = (f16)v;
    t[dd * 530 + o * 8 + e] = cv.u;
  }
  __syncthreads();
  const u32* t32 = (const u32*)t;
  u32* o32 = (u32*)out;
  const int obase = kb << 8;
#pragma unroll 4
  for (int i = 0; i < 32; ++i){
    const int idx = tid + (i << 8);
    const int dd  = idx >> 8;
    const int rem = idx & 255;
    const int o   = rem >> 2;
    const int w   = rem & 3;
    o32[(size_t)dd * (K * 32) + obase + ((o ^ (kb & 3)) << 2) + w] = t32[dd * 265 + rem];
  }
}

// ---------------- CIN step: LDS-B pipelined MFMA GEMM ----------------
// Block: 128 rows x 64 cols, 8 waves.  Wave: 32 rows (2 strips) x 32 cols.
// BK=64 (1 LLDS16/thread/tile), dbuf, counted vmcnt(1).
template<int H>
__global__ __launch_bounds__(512, 4)
void cin_gemm(const f16* __restrict__ xt,     // [32][2048*40] f16
              const f16* __restrict__ xkt,    // [32][2048*64] f16 (H==64)
              const f16* __restrict__ Wp,     // [32][K/8][64'][8] f16 (swizzled)
              const float* __restrict__ bias, // [64]
              f16*       __restrict__ yt)     // [32][2048][64] f16
{
  constexpr int K     = H * 40;
  constexpr int NT    = K / 64;         // 25 or 40 tiles
  constexpr int NG    = K / 320;        // 5 or 8 groups
  constexpr int X0OFF = 16384;
  constexpr int XKOFF = 30720;
  constexpr int XH_MS = (H == 64) ? 2304 : 1792;   // 16 rows * stride
  constexpr int SMEM  = (H == 64) ? 49152 : 30720;

  const int bid = blockIdx.x;
  const int d   = ((bid & 7) << 2) | (bid >> 7);   // XCD-local d groups
  const int bt  = (bid >> 3) & 15;
  const int b0  = bt << 7;
  const int tid = threadIdx.x;
  const int wv  = tid >> 6;
  const int wm  = wv >> 1;              // row strip-of-32 (0..3)
  const int wn  = wv & 1;               // col half (0/1)
  const int l   = tid & 63;
  const int lg  = l >> 4;
  const int ll  = l & 15;

  __shared__ char smem[SMEM];           // [0,16K): B dbuf; x0s@16K; xks@30K

  // ---- issue B tiles 0,1 immediately (overlap x staging) ----
  const f16* gW = Wp + (size_t)d * (K * 64) + wv * 512 + l * 8;
  LLDS16(gW,        smem + wv * 1024);
  LLDS16(gW + 4096, smem + 8192 + wv * 1024);
  const f16* gWn = gW + 8192;           // tile 2 onward

  // ---- stage x0 (and xk) tiles into padded LDS ----
  {
    const uint4* src = (const uint4*)(xt + (size_t)d * 81920 + (size_t)b0 * 40);
#pragma unroll
    for (int it = 0; it < 2; ++it){
      const int idx = tid + (it << 9);
      if (idx < 640){
        const int r = idx / 5, c = idx - r * 5;
        *(uint4*)(smem + X0OFF + r * 112 + c * 16) = src[idx];
      }
    }
  }
  if constexpr (H == 64){
    const uint4* src = (const uint4*)(xkt + (size_t)d * 131072 + (size_t)b0 * 64);
#pragma unroll
    for (int it = 0; it < 2; ++it){
      const int idx = tid + (it << 9);
      const int r = idx >> 3, c = idx & 7;
      *(uint4*)(smem + XKOFF + r * 144 + c * 16) = src[idx];
    }
  }
  __syncthreads();                      // drains vmcnt -> tiles 0,1 landed

  const char* x0b = smem + X0OFF + (wm * 32 + ll) * 112;
  const char* xhb = (H == 64) ? (smem + XKOFF + (wm * 32 + ll) * 144) : x0b;

  // sl[m][sq] = x0 f-block (4*sq+lg)%5 of row wm*32+m*16+ll (stays in VGPRs)
  f16x8 sl[2][5];
#pragma unroll
  for (int m = 0; m < 2; ++m)
#pragma unroll
    for (int sq = 0; sq < 5; ++sq){
      const int j = (4 * sq + lg) % 5;
      sl[m][sq] = *(const f16x8*)(x0b + m * 1792 + j * 16);
    }

  f16x8 xh[2], xhn[2];
#pragma unroll
  for (int m = 0; m < 2; ++m) xh[m] = *(const f16x8*)(xhb + m * XH_MS);

  const f32x4 fz = {0.f, 0.f, 0.f, 0.f};
  f32x4 acc[2][2];
  acc[0][0] = fz; acc[0][1] = fz; acc[1][0] = fz; acc[1][1] = fz;

  // B-frag per-lane byte offset within a tile (o' = o ^ lg swizzle)
  const int vb = lg * 1024 + (((wn << 5) + ll) ^ lg) * 16;

  for (int g = 0; g < NG; ++g){
    // prefetch next group's xh window (safe pad over-read at last group)
#pragma unroll
    for (int m = 0; m < 2; ++m)
      xhn[m] = *(const f16x8*)(xhb + m * XH_MS + (g + 1) * 16);

#pragma unroll
    for (int t_loc = 0; t_loc < 5; ++t_loc){
      const int par = (g + t_loc) & 1;
      const char* bb = smem + par * 8192;
#pragma unroll
      for (int i = 0; i < 2; ++i){
        const f16x8 bf0 = *(const f16x8*)(bb + vb + i * 4096);
        const f16x8 bf1 = *(const f16x8*)(bb + vb + i * 4096 + 256);
        const int siter = t_loc * 2 + i;
        const int sq = siter % 5;
        const int p  = siter / 5;
#pragma unroll
        for (int m = 0; m < 2; ++m){
          f16 xa;
          if (sq == 0)      xa = xh[m][p * 4];
          else if (sq == 4) xa = xh[m][p * 4 + 3];
          else              xa = (lg >= sq) ? xh[m][p * 4 + sq] : xh[m][p * 4 + sq - 1];
          const f16x8 av = sl[m][sq] * xa;
          acc[m][0] = __builtin_amdgcn_mfma_f32_16x16x32_f16(av, bf0, acc[m][0], 0, 0, 0);
          acc[m][1] = __builtin_amdgcn_mfma_f32_16x16x32_f16(av, bf1, acc[m][1], 0, 0, 0);
        }
      }
      FENCE_BAR();                      // all waves done reading buf[par]
      LLDS16(gWn, smem + par * 8192 + wv * 1024);   // stage tile t+2
      gWn += 4096;
      WAITV(1);                         // tile t+1 landed; t+2 in flight
      BAR();
    }
#pragma unroll
    for (int m = 0; m < 2; ++m) xh[m] = xhn[m];
  }

  WAITV(0);                             // drain trailing (garbage) stages
  BAR();

  // ---- epilogue: bias+relu -> per-wave LDS tile -> coalesced 16B stores ----
  const float bv0 = bias[(wn << 5) + ll];
  const float bv1 = bias[(wn << 5) + 16 + ll];
  u16* yw = (u16*)(smem + wv * 3072);   // [32][48] u16 per wave
#pragma unroll
  for (int m = 0; m < 2; ++m)
#pragma unroll
    for (int n = 0; n < 2; ++n)
#pragma unroll
      for (int r = 0; r < 4; ++r){
        const int row = (m << 4) + (lg << 2) + r;
        const int col = (n << 4) + ll;
        float v = acc[m][n][r] + (n ? bv1 : bv0);
        v = v > 0.f ? v : 0.f;
        union { f16 h; u16 u; } cv; cv.h = (f16)v;
        yw[row * 48 + col] = cv.u;
      }
  __syncthreads();
  {
    f16* ydst = yt + (size_t)d * 131072;
#pragma unroll
    for (int j = 0; j < 2; ++j){
      const int rowl = (j << 4) + (l >> 2);
      const int ch   = l & 3;
      const f16x8 vv = *(const f16x8*)((const char*)yw + rowl * 96 + ch * 16);
      *(f16x8*)(ydst + (size_t)(b0 + (wm << 5) + rowl) * 64 + (wn << 5) + (ch << 3)) = vv;
    }
  }
}

// ---------------- final: out[b, :] = sum_d concat(x, x1, x2) ----------------
__global__ __launch_bounds__(192)
void finalize(const float* __restrict__ x, const f16* __restrict__ x1t,
              const f16* __restrict__ y2t, float* __restrict__ out){
  const int b = blockIdx.x;
  const int t = threadIdx.x;
  if (t < 40){
    const float4* p = (const float4*)(x + ((size_t)b * 40 + t) * 32);
    float s = 0.f;
#pragma unroll
    for (int q = 0; q < 8; ++q){
      const float4 v = p[q];
      s += v.x + v.y + v.z + v.w;
    }
    out[(size_t)b * 168 + t] = s;
  } else if (t < 104){
    const int o = t - 40;
    float s = 0.f;
#pragma unroll
    for (int d = 0; d < 32; ++d) s += (float)x1t[(size_t)d * 131072 + (size_t)b * 64 + o];
    out[(size_t)b * 168 + t] = s;
  } else if (t < 168){
    const int o = t - 104;
    float s = 0.f;
#pragma unroll
    for (int d = 0; d < 32; ++d) s += (float)y2t[(size_t)d * 131072 + (size_t)b * 64 + o];
    out[(size_t)b * 168 + t] = s;
  }
}

extern "C" void kernel_launch(void* const* d_in, const int* in_sizes, int n_in,
                              void* d_out, int out_size, void* d_ws, size_t ws_size,
                              hipStream_t stream){
  const float* x   = (const float*)d_in[0];
  const float* W0  = (const float*)d_in[1];
  const float* b0v = (const float*)d_in[2];
  const float* W1  = (const float*)d_in[3];
  const float* b1v = (const float*)d_in[4];
  float* out = (float*)d_out;

  char* ws = (char*)d_ws;
  f16* xt  = (f16*)(ws + 0);            // 32*2048*40*2  =  5,242,880
  f16* W0p = (f16*)(ws + 5242880);      // 32*64*1600*2  =  6,553,600
  f16* W1p = (f16*)(ws + 11796480);     // 32*64*2560*2  = 10,485,760
  f16* x1t = (f16*)(ws + 22282240);     // 32*2048*64*2  =  8,388,608
  f16* y2t = (f16*)(ws + 30670848);     // 32*2048*64*2  =  8,388,608

  transpose32<<<2560, 256, 0, stream>>>(x, xt, 81920);
  wprep<<<200, 256, 0, stream>>>(W0, W0p, 1600);
  wprep<<<320, 256, 0, stream>>>(W1, W1p, 2560);

  cin_gemm<40><<<512, 512, 0, stream>>>(xt, nullptr, W0p, b0v, x1t);
  cin_gemm<64><<<512, 512, 0, stream>>>(xt, x1t,     W1p, b1v, y2t);

  finalize<<<2048, 192, 0, stream>>>(x, x1t, y2t, out);
}

// Round 6
// 69.063 us; speedup vs baseline: 1.9678x; 1.4082x over previous
//
#include <hip/hip_runtime.h>

typedef unsigned int   u32;
typedef unsigned short u16;
typedef _Float16       f16;

using f16x8  = __attribute__((ext_vector_type(8)))  _Float16;
using f16x4  = __attribute__((ext_vector_type(4)))  _Float16;
using f32x16 = __attribute__((ext_vector_type(16))) float;

#define LLDS16(G, L) __builtin_amdgcn_global_load_lds( \
  (const __attribute__((address_space(1))) u32*)(G), \
  (__attribute__((address_space(3))) u32*)(L), 16, 0, 0)

#define WAITV(N) { asm volatile("s_waitcnt vmcnt(" #N ")" ::: "memory"); \
                   __builtin_amdgcn_sched_barrier(0); }
#define FENCE_BAR() { asm volatile("s_waitcnt lgkmcnt(0)" ::: "memory"); \
                      __builtin_amdgcn_sched_barrier(0); \
                      __builtin_amdgcn_s_barrier(); \
                      __builtin_amdgcn_sched_barrier(0); }
#define BAR() { __builtin_amdgcn_s_barrier(); __builtin_amdgcn_sched_barrier(0); }
#define KEEP(x) asm volatile("" : "+v"(x))

// ---------------- transpose (R,32) f32 -> (32,R) f16 ----------------
__global__ __launch_bounds__(256)
void transpose32(const float* __restrict__ in, f16* __restrict__ out, int R){
  __shared__ float tile[32][33];
  const int tid = threadIdx.x;
  const int r0  = blockIdx.x << 5;
  const int c   = tid & 31;
  const int rp  = tid >> 5;
#pragma unroll
  for (int p = 0; p < 4; ++p){
    const int r = (p << 3) + rp;
    tile[r][c] = in[(size_t)(r0 + r) * 32 + c];
  }
  __syncthreads();
#pragma unroll
  for (int p = 0; p < 4; ++p){
    const int dd = (p << 3) + rp;
    out[(size_t)dd * R + r0 + c] = (f16)tile[c][dd];
  }
}

// ------- W (64,K,32) f32 -> k-panel Wp [32][K/8][64][8] f16 (linear) -------
__global__ __launch_bounds__(256)
void wprep(const float* __restrict__ in, f16* __restrict__ out, int K){
  __shared__ u16 t[32 * 530];
  const int kb  = blockIdx.x;           // 0..K/8-1
  const int tid = threadIdx.x;
  const int kbase = kb << 3;
#pragma unroll 4
  for (int i = 0; i < 64; ++i){
    const int idx = tid + (i << 8);
    const int o   = idx >> 8;
    const int rem = idx & 255;
    const int e   = rem >> 5;
    const int dd  = rem & 31;
    const float v = in[(size_t)o * (K * 32) + (size_t)(kbase + e) * 32 + dd];
    union { f16 h; u16 u; } cv; cv.h = (f16)v;
    t[dd * 530 + o * 8 + e] = cv.u;
  }
  __syncthreads();
  const u32* t32 = (const u32*)t;
  u32* o32 = (u32*)out;
  const int obase = kb << 8;
#pragma unroll 4
  for (int i = 0; i < 32; ++i){
    const int idx = tid + (i << 8);
    const int dd  = idx >> 8;
    const int rem = idx & 255;
    o32[(size_t)dd * (K * 32) + obase + rem] = t32[dd * 265 + rem];
  }
}

// ---------------- CIN step: 32x32x16 MFMA, BK=160, dbuf LDS B ----------------
// y[d][b][o] = relu(bias[o] + sum_k xk[b,k/40] * x0[b,k%40] * W[d][o][k])
// Block: 128 rows x 64 cols, 4 waves.  Wave: 32 rows x 64 cols.
template<int H>
__global__ __launch_bounds__(256, 2)
void cin_gemm(const f16* __restrict__ xt,     // [32][2048*40] f16
              const f16* __restrict__ xkt,    // [32][2048*64] f16 (H==64)
              const f16* __restrict__ Wp,     // [32][K/8][64][8] f16
              const float* __restrict__ bias, // [64]
              f16*       __restrict__ yt)     // [32][2048][64] f16
{
  constexpr int K     = H * 40;
  constexpr int NT    = K / 160;        // 10 or 16 tiles of BK=160
  constexpr int X0OFF = 40960;
  constexpr int XKOFF = 55296;
  constexpr int SMEM  = (H == 64) ? 73728 : 55296;

  const int bid = blockIdx.x;
  const int d   = ((bid & 7) << 2) | (bid >> 7);   // XCD-local d groups
  const int b0  = ((bid >> 3) & 15) << 7;
  const int tid = threadIdx.x;
  const int wm  = tid >> 6;             // wave = row strip of 32
  const int l   = tid & 63;
  const int hi  = l >> 5;               // k-run half
  const int lr  = l & 31;               // row / col within 32

  __shared__ char smem[SMEM];           // [0,40960): B dbuf; x0s; xks

  const f16* gW = Wp + (size_t)d * (K * 64);

#define ISSUE_TILE(T, BUF) do { \
    const f16* gt = gW + (size_t)(T) * 10240 + (wm * 64 + l) * 8; \
    char* lb = smem + (BUF) * 20480 + wm * 1024; \
    _Pragma("unroll") \
    for (int i = 0; i < 5; ++i) LLDS16(gt + i * 2048, lb + i * 4096); \
  } while (0)

  ISSUE_TILE(0, 0);
  ISSUE_TILE(1, 1);

  { // stage x0 tile: 128 rows * 80B -> stride 112B
    const uint4* src = (const uint4*)(xt + (size_t)d * 81920 + (size_t)b0 * 40);
#pragma unroll
    for (int it = 0; it < 3; ++it){
      const int idx = tid + (it << 8);
      if (idx < 640){
        const int r = idx / 5, c = idx - r * 5;
        *(uint4*)(smem + X0OFF + r * 112 + c * 16) = src[idx];
      }
    }
  }
  if constexpr (H == 64){ // stage x1 tile: 128 rows * 128B -> stride 144B
    const uint4* src = (const uint4*)(xkt + (size_t)d * 131072 + (size_t)b0 * 64);
#pragma unroll
    for (int it = 0; it < 4; ++it){
      const int idx = tid + (it << 8);
      const int r = idx >> 3, c = idx & 7;
      *(uint4*)(smem + XKOFF + r * 144 + c * 16) = src[idx];
    }
  }
  __syncthreads();                      // drains: tiles 0,1 + x landed

  const char* x0row = smem + X0OFF + (wm * 32 + lr) * 112;
  const char* xhrow = (H == 64) ? (smem + XKOFF + (wm * 32 + lr) * 144) : x0row;

  // sl[t] = x0 f-block (t+hi)%5 of this lane's row (pinned in VGPRs)
  f16x8 sl[5];
  {
    const char* xe = x0row + hi * 16;
#pragma unroll
    for (int t = 0; t < 4; ++t) sl[t] = *(const f16x8*)(xe + t * 16);
    sl[4] = *(const f16x8*)(x0row + (hi ? 0 : 64));
  }
  KEEP(sl[0]); KEEP(sl[1]); KEEP(sl[2]); KEEP(sl[3]); KEEP(sl[4]);

  f16x4 xh = *(const f16x4*)(xhrow);    // h window for tile 0

  f32x16 acc0 = {0,0,0,0,0,0,0,0,0,0,0,0,0,0,0,0};
  f32x16 acc1 = {0,0,0,0,0,0,0,0,0,0,0,0,0,0,0,0};

  const int bvb = hi * 1024 + lr * 16;  // B-frag lane base within a tile

  // per-s-iter tables: q = si*4 (+2 for second khalf); j=q%5, h=q/5
  static constexpr int J0[5]  = {0, 4, 3, 2, 1};
  static constexpr int H0[5]  = {0, 0, 1, 2, 3};
  static constexpr int H0b[5] = {0, 1, 1, 2, 3};
  static constexpr int S0[5]  = {0, 1, 0, 0, 0};
  static constexpr int J2[5]  = {2, 1, 0, 4, 3};
  static constexpr int H2[5]  = {0, 1, 2, 2, 3};
  static constexpr int H2b[5] = {0, 1, 2, 3, 3};
  static constexpr int S2[5]  = {0, 0, 0, 1, 0};

  for (int t = 0; t < NT; ++t){
    const char* bb = smem + (t & 1) * 20480 + bvb;
    const f16x4 xhn = *(const f16x4*)(xhrow + (t + 1) * 8);  // pad-safe
#pragma unroll
    for (int si = 0; si < 5; ++si){
      const f16x8 b00 = *(const f16x8*)(bb + (si * 4) * 1024);
      const f16x8 b01 = *(const f16x8*)(bb + (si * 4) * 1024 + 512);
      const f16x8 b20 = *(const f16x8*)(bb + (si * 4 + 2) * 1024);
      const f16x8 b21 = *(const f16x8*)(bb + (si * 4 + 2) * 1024 + 512);
      const f16 xa0 = (S0[si] && hi) ? xh[H0b[si]] : xh[H0[si]];
      const f16 xa2 = (S2[si] && hi) ? xh[H2b[si]] : xh[H2[si]];
      const f16x8 av0 = sl[J0[si]] * xa0;
      const f16x8 av2 = sl[J2[si]] * xa2;
      acc0 = __builtin_amdgcn_mfma_f32_32x32x16_f16(av0, b00, acc0, 0, 0, 0);
      acc1 = __builtin_amdgcn_mfma_f32_32x32x16_f16(av0, b01, acc1, 0, 0, 0);
      acc0 = __builtin_amdgcn_mfma_f32_32x32x16_f16(av2, b20, acc0, 0, 0, 0);
      acc1 = __builtin_amdgcn_mfma_f32_32x32x16_f16(av2, b21, acc1, 0, 0, 0);
    }
    FENCE_BAR();                        // all waves done reading buf[t&1]
    if (t + 2 < NT){
      ISSUE_TILE(t + 2, t & 1);
      WAITV(5);                         // tile t+1 landed; t+2 in flight
    } else {
      WAITV(0);
    }
    BAR();
    xh = xhn;
  }

  // ---- epilogue: bias+relu -> per-wave LDS [32][72] -> coalesced stores ----
  const float bv0 = bias[lr];
  const float bv1 = bias[lr + 32];
  u16* yw = (u16*)(smem + wm * 4608);
#pragma unroll
  for (int reg = 0; reg < 16; ++reg){
    const int row = (reg & 3) + 8 * (reg >> 2) + 4 * hi;
    float v0 = acc0[reg] + bv0; v0 = v0 > 0.f ? v0 : 0.f;
    float v1 = acc1[reg] + bv1; v1 = v1 > 0.f ? v1 : 0.f;
    union { f16 h; u16 u; } c0, c1; c0.h = (f16)v0; c1.h = (f16)v1;
    yw[row * 72 + lr]      = c0.u;
    yw[row * 72 + lr + 32] = c1.u;
  }
  __syncthreads();
  {
    f16* ydst = yt + (size_t)d * 131072;
#pragma unroll
    for (int j = 0; j < 4; ++j){
      const int row = j * 8 + (l >> 3);
      const int ch  = l & 7;
      const f16x8 vv = *(const f16x8*)((const char*)yw + row * 144 + ch * 16);
      *(f16x8*)(ydst + (size_t)(b0 + wm * 32 + row) * 64 + ch * 8) = vv;
    }
  }
#undef ISSUE_TILE
}

// ---------------- final: out[b, :] = sum_d concat(x, x1, x2) ----------------
__global__ __launch_bounds__(192)
void finalize(const float* __restrict__ x, const f16* __restrict__ x1t,
              const f16* __restrict__ y2t, float* __restrict__ out){
  const int b = blockIdx.x;
  const int t = threadIdx.x;
  if (t < 40){
    const float4* p = (const float4*)(x + ((size_t)b * 40 + t) * 32);
    float s = 0.f;
#pragma unroll
    for (int q = 0; q < 8; ++q){
      const float4 v = p[q];
      s += v.x + v.y + v.z + v.w;
    }
    out[(size_t)b * 168 + t] = s;
  } else if (t < 104){
    const int o = t - 40;
    float s = 0.f;
#pragma unroll
    for (int d = 0; d < 32; ++d) s += (float)x1t[(size_t)d * 131072 + (size_t)b * 64 + o];
    out[(size_t)b * 168 + t] = s;
  } else if (t < 168){
    const int o = t - 104;
    float s = 0.f;
#pragma unroll
    for (int d = 0; d < 32; ++d) s += (float)y2t[(size_t)d * 131072 + (size_t)b * 64 + o];
    out[(size_t)b * 168 + t] = s;
  }
}

extern "C" void kernel_launch(void* const* d_in, const int* in_sizes, int n_in,
                              void* d_out, int out_size, void* d_ws, size_t ws_size,
                              hipStream_t stream){
  const float* x   = (const float*)d_in[0];
  const float* W0  = (const float*)d_in[1];
  const float* b0v = (const float*)d_in[2];
  const float* W1  = (const float*)d_in[3];
  const float* b1v = (const float*)d_in[4];
  float* out = (float*)d_out;

  char* ws = (char*)d_ws;
  f16* xt  = (f16*)(ws + 0);            // 32*2048*40*2  =  5,242,880
  f16* W0p = (f16*)(ws + 5242880);      // 32*64*1600*2  =  6,553,600
  f16* W1p = (f16*)(ws + 11796480);     // 32*64*2560*2  = 10,485,760
  f16* x1t = (f16*)(ws + 22282240);     // 32*2048*64*2  =  8,388,608
  f16* y2t = (f16*)(ws + 30670848);     // 32*2048*64*2  =  8,388,608

  transpose32<<<2560, 256, 0, stream>>>(x, xt, 81920);
  wprep<<<200, 256, 0, stream>>>(W0, W0p, 1600);
  wprep<<<320, 256, 0, stream>>>(W1, W1p, 2560);

  cin_gemm<40><<<512, 256, 0, stream>>>(xt, nullptr, W0p, b0v, x1t);
  cin_gemm<64><<<512, 256, 0, stream>>>(xt, x1t,     W1p, b1v, y2t);

  finalize<<<2048, 192, 0, stream>>>(x, x1t, y2t, out);
}

// Round 7
// 62.746 us; speedup vs baseline: 2.1659x; 1.1007x over previous
//
#include <hip/hip_runtime.h>

typedef unsigned int   u32;
typedef unsigned short u16;
typedef _Float16       f16;

using f16x8  = __attribute__((ext_vector_type(8)))  _Float16;
using f32x16 = __attribute__((ext_vector_type(16))) float;

#define LLDS16(G, L) __builtin_amdgcn_global_load_lds( \
  (const __attribute__((address_space(1))) u32*)(G), \
  (__attribute__((address_space(3))) u32*)(L), 16, 0, 0)

#define WAITV(N) { asm volatile("s_waitcnt vmcnt(" #N ")" ::: "memory"); \
                   __builtin_amdgcn_sched_barrier(0); }
#define FENCE_BAR() { asm volatile("s_waitcnt lgkmcnt(0)" ::: "memory"); \
                      __builtin_amdgcn_sched_barrier(0); \
                      __builtin_amdgcn_s_barrier(); \
                      __builtin_amdgcn_sched_barrier(0); }
#define BAR() { __builtin_amdgcn_s_barrier(); __builtin_amdgcn_sched_barrier(0); }
#define KEEP(x) asm volatile("" : "+v"(x))

// ------- x prep: transpose (81920,32) f32 -> (32,81920) f16, + row sums -------
// Also computes out[b][f] = sum_d x[b][f][d] for the concat's x segment.
__global__ __launch_bounds__(256)
void xprep(const float* __restrict__ in, f16* __restrict__ out,
           float* __restrict__ osum){
  __shared__ float tile[32][33];
  const int tid = threadIdx.x;
  const int r0  = blockIdx.x << 5;
  const int c   = tid & 31;
  const int rp  = tid >> 5;
#pragma unroll
  for (int p = 0; p < 4; ++p){
    const int r = (p << 3) + rp;
    float v = in[(size_t)(r0 + r) * 32 + c];
    tile[r][c] = v;
    float s = v;
#pragma unroll
    for (int off = 16; off > 0; off >>= 1) s += __shfl_xor(s, off, 32);
    if (c == 0){
      const int row = r0 + r;              // = b*40 + f
      osum[(size_t)(row / 40) * 168 + (row % 40)] = s;
    }
  }
  __syncthreads();
#pragma unroll
  for (int p = 0; p < 4; ++p){
    const int dd = (p << 3) + rp;
    out[(size_t)dd * 81920 + r0 + c] = (f16)tile[c][dd];
  }
}

// ------- W (64,K,32) f32 -> k-panel Wp [32][K/8][64][8] f16 (merged W0+W1) ----
__global__ __launch_bounds__(256)
void wprep(const float* __restrict__ W0, const float* __restrict__ W1,
           f16* __restrict__ out0, f16* __restrict__ out1){
  __shared__ u16 t[32 * 530];
  int kb = blockIdx.x;
  const float* in; f16* out; int K;
  if (kb < 200){ in = W0; out = out0; K = 1600; }
  else         { kb -= 200; in = W1; out = out1; K = 2560; }
  const int tid = threadIdx.x;
  const int kbase = kb << 3;
#pragma unroll 4
  for (int i = 0; i < 64; ++i){
    const int idx = tid + (i << 8);
    const int o   = idx >> 8;
    const int rem = idx & 255;
    const int e   = rem >> 5;
    const int dd  = rem & 31;
    const float v = in[(size_t)o * (K * 32) + (size_t)(kbase + e) * 32 + dd];
    union { f16 h; u16 u; } cv; cv.h = (f16)v;
    t[dd * 530 + o * 8 + e] = cv.u;
  }
  __syncthreads();
  const u32* t32 = (const u32*)t;
  u32* o32 = (u32*)out;
  const int obase = kb << 8;
#pragma unroll 4
  for (int i = 0; i < 32; ++i){
    const int idx = tid + (i << 8);
    const int dd  = idx >> 8;
    const int rem = idx & 255;
    o32[(size_t)dd * (K * 32) + obase + rem] = t32[dd * 265 + rem];
  }
}

// ---------------- CIN step: 32x32x16 MFMA, BK=320, dbuf LDS B ----------------
// y[d][b][o] = relu(bias[o] + sum_k xk[b,k/40] * x0[b,k%40] * W[d][o][k])
// Block: 256 rows x 64 cols, 8 waves.  Wave: 64 rows (2 strips) x 32 cols.
template<int H>
__global__ __launch_bounds__(512, 2)
void cin_gemm(const f16* __restrict__ xt,     // [32][2048*40] f16
              const f16* __restrict__ xkt,    // [32][2048*64] f16 (H==64)
              const f16* __restrict__ Wp,     // [32][K/8][64][8] f16
              const float* __restrict__ bias, // [64]
              f16*       __restrict__ yt)     // [32][2048][64] f16
{
  constexpr int K     = H * 40;
  constexpr int NT    = K / 320;        // 5 or 8 tiles
  constexpr int X0OFF = 81920;          // 2 x 40KB B dbuf below
  constexpr int XKOFF = 110592;         // X0OFF + 256*112
  constexpr int X0MS  = 32 * 112;
  constexpr int XHMS  = (H == 64) ? 32 * 144 : 32 * 112;
  constexpr int SMEM  = (H == 64) ? 147456 : 110592;

  const int bid = blockIdx.x;
  const int d   = ((bid & 7) << 2) | ((bid >> 3) & 3);   // XCD-local d groups
  const int b0  = (bid >> 5) << 8;      // 8 b-tiles of 256 rows
  const int tid = threadIdx.x;
  const int wv  = tid >> 6;             // 0..7
  const int wr  = wv >> 1;              // row quarter (64 rows)
  const int wc  = wv & 1;               // col half (32 cols)
  const int l   = tid & 63;
  const int hi  = l >> 5;               // k-run half
  const int lr  = l & 31;               // row / col within 32

  __shared__ char smem[SMEM];

  const f16* gW = Wp + (size_t)d * (K * 64);

#define ISSUE_TILE(T, BUF) do { \
    const f16* gt = gW + (size_t)(T) * 20480 + wv * 2560 + l * 8; \
    char* lb = smem + (BUF) * 40960 + wv * 5120; \
    _Pragma("unroll") \
    for (int i = 0; i < 5; ++i) LLDS16(gt + i * 512, lb + i * 1024); \
  } while (0)

  ISSUE_TILE(0, 0);
  ISSUE_TILE(1, 1);

  { // stage x0 tile: 256 rows * 80B -> stride 112B
    const uint4* src = (const uint4*)(xt + (size_t)d * 81920 + (size_t)b0 * 40);
#pragma unroll
    for (int it = 0; it < 3; ++it){
      const int idx = tid + (it << 9);
      if (idx < 1280){
        const int r = idx / 5, c = idx - r * 5;
        *(uint4*)(smem + X0OFF + r * 112 + c * 16) = src[idx];
      }
    }
  }
  if constexpr (H == 64){ // stage x1 tile: 256 rows * 128B -> stride 144B
    const uint4* src = (const uint4*)(xkt + (size_t)d * 131072 + (size_t)b0 * 64);
#pragma unroll
    for (int it = 0; it < 4; ++it){
      const int idx = tid + (it << 9);
      const int r = idx >> 3, c = idx & 7;
      *(uint4*)(smem + XKOFF + r * 144 + c * 16) = src[idx];
    }
  }
  __syncthreads();                      // drains vmcnt: tiles 0,1 + x landed

  const char* x0row = smem + X0OFF + (wr * 64 + lr) * 112;
  const char* xhrow = (H == 64) ? (smem + XKOFF + (wr * 64 + lr) * 144) : x0row;

  // sl[m][t] = x0 f-block (t+hi)%5 of strip-m row (pinned in VGPRs)
  f16x8 sl[2][5];
#pragma unroll
  for (int m = 0; m < 2; ++m){
    const char* xe = x0row + m * X0MS + hi * 16;
#pragma unroll
    for (int t = 0; t < 4; ++t) sl[m][t] = *(const f16x8*)(xe + t * 16);
    sl[m][4] = *(const f16x8*)(x0row + m * X0MS + (hi ? 0 : 64));
  }
  KEEP(sl[0][0]); KEEP(sl[0][1]); KEEP(sl[0][2]); KEEP(sl[0][3]); KEEP(sl[0][4]);
  KEEP(sl[1][0]); KEEP(sl[1][1]); KEEP(sl[1][2]); KEEP(sl[1][3]); KEEP(sl[1][4]);

  f16x8 xh0 = *(const f16x8*)(xhrow);
  f16x8 xh1 = *(const f16x8*)(xhrow + XHMS);

  f32x16 acc0 = {0,0,0,0,0,0,0,0,0,0,0,0,0,0,0,0};
  f32x16 acc1 = {0,0,0,0,0,0,0,0,0,0,0,0,0,0,0,0};

  const int vb = hi * 1024 + wc * 512 + lr * 16;

  // k-run r8 = si*4 + kh*2 + hi; j = r8%5 (via hi-rotated sl), h = r8/5
  static constexpr int J0[10]  = {0,4,3,2,1,0,4,3,2,1};
  static constexpr int H0[10]  = {0,0,1,2,3,4,4,5,6,7};
  static constexpr int H0b[10] = {0,1,1,2,3,4,5,5,6,7};
  static constexpr int S0[10]  = {0,1,0,0,0,0,1,0,0,0};
  static constexpr int J2[10]  = {2,1,0,4,3,2,1,0,4,3};
  static constexpr int H2[10]  = {0,1,2,2,3,4,5,6,6,7};
  static constexpr int H2b[10] = {0,1,2,3,3,4,5,6,7,7};
  static constexpr int S2[10]  = {0,0,0,1,0,0,0,0,1,0};

  for (int t = 0; t < NT; ++t){
    const char* bb = smem + (t & 1) * 40960 + vb;
    const f16x8 xhn0 = *(const f16x8*)(xhrow + (t + 1) * 16);          // pad-safe
    const f16x8 xhn1 = *(const f16x8*)(xhrow + XHMS + (t + 1) * 16);
#pragma unroll
    for (int si = 0; si < 10; ++si){
      const f16x8 bf0 = *(const f16x8*)(bb + (si * 4) * 1024);
      const f16x8 bf2 = *(const f16x8*)(bb + (si * 4 + 2) * 1024);
      const f16 xa00 = (S0[si] && hi) ? xh0[H0b[si]] : xh0[H0[si]];
      const f16 xa01 = (S0[si] && hi) ? xh1[H0b[si]] : xh1[H0[si]];
      const f16 xa20 = (S2[si] && hi) ? xh0[H2b[si]] : xh0[H2[si]];
      const f16 xa21 = (S2[si] && hi) ? xh1[H2b[si]] : xh1[H2[si]];
      acc0 = __builtin_amdgcn_mfma_f32_32x32x16_f16(sl[0][J0[si]] * xa00, bf0, acc0, 0, 0, 0);
      acc1 = __builtin_amdgcn_mfma_f32_32x32x16_f16(sl[1][J0[si]] * xa01, bf0, acc1, 0, 0, 0);
      acc0 = __builtin_amdgcn_mfma_f32_32x32x16_f16(sl[0][J2[si]] * xa20, bf2, acc0, 0, 0, 0);
      acc1 = __builtin_amdgcn_mfma_f32_32x32x16_f16(sl[1][J2[si]] * xa21, bf2, acc1, 0, 0, 0);
    }
    FENCE_BAR();                        // all waves done reading buf[t&1]
    if (t + 2 < NT){
      ISSUE_TILE(t + 2, t & 1);
      WAITV(5);                         // tile t+1 landed; t+2 in flight
    } else {
      WAITV(0);
    }
    BAR();
    xh0 = xhn0; xh1 = xhn1;
  }

  // ---- epilogue: bias+relu -> per-wave LDS [64][36] -> coalesced stores ----
  const float bv = bias[(wc << 5) + lr];
  u16* yw = (u16*)(smem + wv * 4608);
#pragma unroll
  for (int m = 0; m < 2; ++m)
#pragma unroll
    for (int reg = 0; reg < 16; ++reg){
      const int row = (m << 5) + (reg & 3) + ((reg >> 2) << 3) + (hi << 2);
      float v = (m ? acc1[reg] : acc0[reg]) + bv;
      v = v > 0.f ? v : 0.f;
      union { f16 h; u16 u; } cv; cv.h = (f16)v;
      yw[row * 36 + lr] = cv.u;
    }
  asm volatile("s_waitcnt lgkmcnt(0)" ::: "memory");
  {
    f16* ydst = yt + (size_t)d * 131072;
#pragma unroll
    for (int j = 0; j < 4; ++j){
      const int row = (j << 4) + (l >> 2);
      const int ch  = l & 3;
      const f16x8 vv = *(const f16x8*)((const char*)yw + row * 72 + ch * 16);
      *(f16x8*)(ydst + (size_t)(b0 + (wr << 6) + row) * 64 + (wc << 5) + (ch << 3)) = vv;
    }
  }
#undef ISSUE_TILE
}

// ---------------- final: out[b, 40:168] = sum_d concat(x1, x2) ----------------
__global__ __launch_bounds__(128)
void finalize(const f16* __restrict__ x1t, const f16* __restrict__ y2t,
              float* __restrict__ out){
  const int b = blockIdx.x;
  const int t = threadIdx.x;
  if (t < 64){
    float s = 0.f;
#pragma unroll
    for (int d = 0; d < 32; ++d) s += (float)x1t[(size_t)d * 131072 + (size_t)b * 64 + t];
    out[(size_t)b * 168 + 40 + t] = s;
  } else {
    const int o = t - 64;
    float s = 0.f;
#pragma unroll
    for (int d = 0; d < 32; ++d) s += (float)y2t[(size_t)d * 131072 + (size_t)b * 64 + o];
    out[(size_t)b * 168 + 104 + o] = s;
  }
}

extern "C" void kernel_launch(void* const* d_in, const int* in_sizes, int n_in,
                              void* d_out, int out_size, void* d_ws, size_t ws_size,
                              hipStream_t stream){
  const float* x   = (const float*)d_in[0];
  const float* W0  = (const float*)d_in[1];
  const float* b0v = (const float*)d_in[2];
  const float* W1  = (const float*)d_in[3];
  const float* b1v = (const float*)d_in[4];
  float* out = (float*)d_out;

  char* ws = (char*)d_ws;
  f16* xt  = (f16*)(ws + 0);            // 32*2048*40*2  =  5,242,880
  f16* W0p = (f16*)(ws + 5242880);      // 32*64*1600*2  =  6,553,600
  f16* W1p = (f16*)(ws + 11796480);     // 32*64*2560*2  = 10,485,760
  f16* x1t = (f16*)(ws + 22282240);     // 32*2048*64*2  =  8,388,608
  f16* y2t = (f16*)(ws + 30670848);     // 32*2048*64*2  =  8,388,608

  xprep<<<2560, 256, 0, stream>>>(x, xt, out);
  wprep<<<520, 256, 0, stream>>>(W0, W1, W0p, W1p);

  cin_gemm<40><<<256, 512, 0, stream>>>(xt, nullptr, W0p, b0v, x1t);
  cin_gemm<64><<<256, 512, 0, stream>>>(xt, x1t,     W1p, b1v, y2t);

  finalize<<<2048, 128, 0, stream>>>(x1t, y2t, out);
}